// Round 1
// baseline (1640.804 us; speedup 1.0000x reference)
//
#include <hip/hip_runtime.h>
#include <cstdint>
#include <cstddef>

// ---------------------------------------------------------------------------
// OrderedMemoryDecoder (DEPTH=14, B=8, H=1024, V=32000) for gfx950.
// Phases: static structure (constexpr), init (g,h0), gW precompute, 13 tree
// levels (split-K fp32 GEMM + fused LN/tanh/leaf), bf16 MFMA output GEMM,
// two-pass log-softmax, index outputs.
// ---------------------------------------------------------------------------

typedef __attribute__((ext_vector_type(4))) float   f4;
typedef __attribute__((ext_vector_type(4))) float   f32x4;
typedef __attribute__((ext_vector_type(8))) __bf16  bf16x8;
typedef __attribute__((ext_vector_type(4))) unsigned short us4;

constexpr int DEPTH = 14;
constexpr int Bb = 8;
constexpr int Hd = 1024;
constexpr int Vv = 32000;
constexpr int MAXT = 512;
constexpr int MAXS = 4096;
constexpr int MAXP = 32;

struct SB {
  int lvlOff[DEPTH + 1];
  int lvlK[DEPTH];
  int len[MAXT];
  int lch[MAXT], rch[MAXT];
  int parCnt[DEPTH];
  int parRows[DEPTH][MAXP];
  int T;
  int nS;
  int sOut[MAXS], sIn[MAXS];
  int nStart, nEnd;
  int startIdx[16], endIdx[16];
};

constexpr int ceil75(int L) {
  // ceil(L^0.75) for L in 0..13 (values safely away from integer boundaries)
  constexpr int t[14] = {0, 1, 2, 3, 3, 4, 4, 5, 5, 6, 6, 7, 7, 7};
  return t[L];
}

constexpr SB build() {
  SB s{};
  for (int i = 0; i < MAXT; i++) { s.lch[i] = -1; s.rch[i] = -1; }
  s.lvlOff[0] = 0; s.lvlK[0] = 1; s.len[0] = DEPTH;
  for (int l = 0; l < DEPTH - 1; l++) {
    int off = s.lvlOff[l], K = s.lvlK[l];
    int nxt = off + K, cnt = 0;
    for (int i = 0; i < K; i++) {
      int g = off + i;
      if (s.len[g] > 1) {
        int gl = nxt + 2 * cnt, gr = gl + 1;
        s.lch[g] = gl; s.rch[g] = gr;
        s.len[gl] = ceil75(s.len[g] - 1);  // left child: ceil((L-1)^0.75)
        s.len[gr] = s.len[g] - 1;          // right child: L-1
        s.parRows[l][cnt] = g;
        cnt++;
      }
    }
    s.parCnt[l] = cnt;
    s.lvlOff[l + 1] = nxt;
    s.lvlK[l + 1] = 2 * cnt;
  }
  s.T = s.lvlOff[DEPTH - 1] + s.lvlK[DEPTH - 1];
  // S pairs: recursion appends deepest level's parents first, root last.
  // Per parent g: for v_i in B_r[lch(g)] (right-chain), v_j in B_l[rch(g)].
  s.nS = 0;
  for (int l = DEPTH - 2; l >= 0; l--) {
    for (int pi = 0; pi < s.parCnt[l]; pi++) {
      int g = s.parRows[l][pi];
      for (int u = s.lch[g]; u != -1; u = s.rch[u])
        for (int v = s.rch[g]; v != -1; v = s.lch[v]) {
          s.sOut[s.nS] = u; s.sIn[s.nS] = v; s.nS++;
        }
    }
  }
  s.nStart = 0;
  for (int u = 0; u != -1; u = s.lch[u]) s.startIdx[s.nStart++] = u;
  s.nEnd = 0;
  for (int u = 0; u != -1; u = s.rch[u]) s.endIdx[s.nEnd++] = u;
  return s;
}

constexpr SB HS = build();          // host copy (launch shapes)
__device__ const SB DS = build();   // device copy (index outputs)

struct PR { int v[MAXP]; };

__device__ __forceinline__ unsigned short f2bf(float f) {
  union { float f; unsigned u; } v; v.f = f;
  unsigned r = v.u + 0x7fffu + ((v.u >> 16) & 1u);  // RNE
  return (unsigned short)(r >> 16);
}

// --------------------------- W_out -> bf16, transposed ----------------------
// Wt[n][k] = bf16(W_out[k][n]); gives k-contiguous B^T layout for MFMA frags.
__global__ void k_wout_t(const float* __restrict__ Wout,
                         unsigned short* __restrict__ Wt) {
  __shared__ float t[32][33];
  int tx = threadIdx.x, ty = threadIdx.y;
  int n0 = blockIdx.x * 32, k0 = blockIdx.y * 32;
  for (int i = 0; i < 4; i++)
    t[ty + 8 * i][tx] = Wout[(size_t)(k0 + ty + 8 * i) * Vv + n0 + tx];
  __syncthreads();
  for (int i = 0; i < 4; i++)
    Wt[(size_t)(n0 + ty + 8 * i) * Hd + k0 + tx] = f2bf(t[tx][ty + 8 * i]);
}

// ------------------------------ g and h0 ------------------------------------
__global__ void k_init(const float* __restrict__ x, const float* __restrict__ Wg,
                       const float* __restrict__ bg, const float* __restrict__ Win,
                       const float* __restrict__ bin, float* __restrict__ gbuf,
                       float* __restrict__ hidd, unsigned short* __restrict__ hiddb) {
  __shared__ float xs[Bb * Hd];
  __shared__ float part[Bb][128];
  int tid = threadIdx.x;
  int mat = blockIdx.y;  // 0: g = x@W_g+b_g ; 1: h0 = x@W_in+b_in
  const float* W = mat ? Win : Wg;
  const float* bias = mat ? bin : bg;
  for (int i = tid; i < Bb * Hd; i += 256) xs[i] = x[i];
  __syncthreads();
  int c = tid & 127, kh = tid >> 7;
  int col = blockIdx.x * 128 + c;
  float acc[Bb];
#pragma unroll
  for (int b = 0; b < Bb; b++) acc[b] = 0.f;
  for (int k = kh * 512; k < kh * 512 + 512; k++) {
    float w = W[(size_t)k * Hd + col];
#pragma unroll
    for (int b = 0; b < Bb; b++) acc[b] += xs[b * Hd + k] * w;
  }
  if (kh == 1)
    for (int b = 0; b < Bb; b++) part[b][c] = acc[b];
  __syncthreads();
  if (kh == 0) {
    for (int b = 0; b < Bb; b++) {
      float v = acc[b] + part[b][c] + bias[col];
      if (mat == 0) gbuf[b * Hd + col] = v;
      else { hidd[(size_t)b * Hd + col] = v; hiddb[(size_t)b * Hd + col] = f2bf(v); }
    }
  }
}

// --------------------- gW = g @ W_cell[1024:,:] + b_cell --------------------
__global__ void k_gw(const float* __restrict__ gbuf, const float* __restrict__ Wc,
                     const float* __restrict__ bc, float* __restrict__ gW) {
  __shared__ float xs[Bb * Hd];
  __shared__ float part[Bb][128];
  int tid = threadIdx.x;
  for (int i = tid; i < Bb * Hd; i += 256) xs[i] = gbuf[i];
  __syncthreads();
  int c = tid & 127, kh = tid >> 7;
  int col = blockIdx.x * 128 + c;  // 0..2047
  float acc[Bb];
#pragma unroll
  for (int b = 0; b < Bb; b++) acc[b] = 0.f;
  for (int k = kh * 512; k < kh * 512 + 512; k++) {
    float w = Wc[(size_t)(Hd + k) * 2048 + col];
#pragma unroll
    for (int b = 0; b < Bb; b++) acc[b] += xs[b * Hd + k] * w;
  }
  if (kh == 1)
    for (int b = 0; b < Bb; b++) part[b][c] = acc[b];
  __syncthreads();
  if (kh == 0)
    for (int b = 0; b < Bb; b++)
      gW[(size_t)b * 2048 + col] = acc[b] + part[b][c] + bc[col];
}

// ---------------------- level-0 leaf log-softmax ----------------------------
__global__ void k_leaf0(const float* __restrict__ hidd, const float* __restrict__ Wl,
                        const float* __restrict__ bl, float* __restrict__ leaves) {
  int b = threadIdx.x >> 6, lane = threadIdx.x & 63;
  float d0 = 0.f, d1 = 0.f;
  for (int k = lane; k < Hd; k += 64) {
    float h = hidd[(size_t)b * Hd + k];
    d0 += h * Wl[2 * k];
    d1 += h * Wl[2 * k + 1];
  }
  for (int off = 32; off; off >>= 1) {
    d0 += __shfl_down(d0, off);
    d1 += __shfl_down(d1, off);
  }
  if (lane == 0) {
    float l0 = d0 + bl[0], l1 = d1 + bl[1];
    float m = fmaxf(l0, l1);
    float L = logf(expf(l0 - m) + expf(l1 - m));
    leaves[b * 2 + 0] = l0 - m - L;
    leaves[b * 2 + 1] = l1 - m - L;
  }
}

// -------------------- tree cell: split-K partial z --------------------------
// block (cg, p, ks): partial z for parent p, cols cg*1024+[0,1024), K-chunk ks.
__global__ void k_cell(const float* __restrict__ hidd, const float* __restrict__ Wc,
                       float* __restrict__ zp, PR pr, int KS, int kshift) {
  __shared__ float hs[Bb * 128];
  int tid = threadIdx.x;
  int cg = blockIdx.x, p = blockIdx.y, ks = blockIdx.z;
  int gp = pr.v[p];
  int kchunk = 1 << kshift;
  int koff = ks << kshift;
  for (int i = tid; i < Bb * kchunk; i += 256) {
    int b = i >> kshift, k = i & (kchunk - 1);
    hs[i] = hidd[((size_t)gp * Bb + b) * Hd + koff + k];
  }
  __syncthreads();
  int col0 = cg * 1024 + tid * 4;
  f4 acc[Bb];
#pragma unroll
  for (int b = 0; b < Bb; b++) acc[b] = 0.f;
  for (int k = 0; k < kchunk; k++) {
    f4 w = *(const f4*)&Wc[(size_t)(koff + k) * 2048 + col0];
#pragma unroll
    for (int b = 0; b < Bb; b++) {
      float h = hs[(b << kshift) | k];
      acc[b] += h * w;
    }
  }
  int node = 2 * p + cg;
  size_t base = ((size_t)node * KS + ks) * Bb * 1024;
#pragma unroll
  for (int b = 0; b < Bb; b++)
    *(f4*)&zp[base + (size_t)b * 1024 + tid * 4] = acc[b];
}

// ---------- tree LN+tanh+leaf: one block per (child node, batch) ------------
__global__ void k_ln(const float* __restrict__ zp, const float* __restrict__ gW,
                     const float* __restrict__ lng, const float* __restrict__ lnb,
                     const float* __restrict__ Wl, const float* __restrict__ bl,
                     float* __restrict__ hidd, unsigned short* __restrict__ hiddb,
                     float* __restrict__ leaves, PR pr, int KS, int lvlOff) {
  __shared__ float r1[256], r2[256];
  int tid = threadIdx.x;
  int node = blockIdx.x, b = blockIdx.y;
  int cg = node & 1, p = node >> 1;
  int gp = pr.v[p];
  int ch = lvlOff + node;
  int j0 = tid * 4;
  f4 z = 0.f;
  for (int ks = 0; ks < KS; ks++)
    z += *(const f4*)&zp[(((size_t)node * KS + ks) * Bb + b) * 1024 + j0];
  z += *(const f4*)&gW[(size_t)b * 2048 + cg * 1024 + j0];
  float s = z.x + z.y + z.z + z.w;
  float s2 = z.x * z.x + z.y * z.y + z.z * z.z + z.w * z.w;
  r1[tid] = s; r2[tid] = s2;
  __syncthreads();
  for (int o = 128; o; o >>= 1) {
    if (tid < o) { r1[tid] += r1[tid + o]; r2[tid] += r2[tid + o]; }
    __syncthreads();
  }
  float mu = r1[0] * (1.f / 1024.f);
  float var = r2[0] * (1.f / 1024.f) - mu * mu;
  float rs = rsqrtf(var + 1e-5f);
  __syncthreads();  // done reading r1/r2 before reuse
  f4 lgv = *(const f4*)&lng[j0];
  f4 lbv = *(const f4*)&lnb[j0];
  f4 y;
  y.x = tanhf((z.x - mu) * rs * lgv.x + lbv.x);
  y.y = tanhf((z.y - mu) * rs * lgv.y + lbv.y);
  y.z = tanhf((z.z - mu) * rs * lgv.z + lbv.z);
  y.w = tanhf((z.w - mu) * rs * lgv.w + lbv.w);
  *(f4*)&hidd[((size_t)ch * Bb + b) * Hd + j0] = y;
  us4 yb;
  yb.x = f2bf(y.x); yb.y = f2bf(y.y); yb.z = f2bf(y.z); yb.w = f2bf(y.w);
  *(us4*)&hiddb[((size_t)ch * Bb + b) * Hd + j0] = yb;
  // leaf dot over this thread's 4 cols (W_leaf is [1024][2] row-major)
  f4 wA = *(const f4*)&Wl[j0 * 2];
  f4 wB = *(const f4*)&Wl[j0 * 2 + 4];
  float d0 = y.x * wA.x + y.y * wA.z + y.z * wB.x + y.w * wB.z;
  float d1 = y.x * wA.y + y.y * wA.w + y.z * wB.y + y.w * wB.w;
  r1[tid] = d0; r2[tid] = d1;
  __syncthreads();
  for (int o = 128; o; o >>= 1) {
    if (tid < o) { r1[tid] += r1[tid + o]; r2[tid] += r2[tid + o]; }
    __syncthreads();
  }
  if (tid == 0) {
    float l0 = r1[0] + bl[0], l1 = r2[0] + bl[1];
    float m = fmaxf(l0, l1);
    float L = logf(expf(l0 - m) + expf(l1 - m));
    float half = 0.5f * leaves[((size_t)gp * Bb + b) * 2 + 1];
    leaves[((size_t)ch * Bb + b) * 2 + 0] = half + l0 - m - L;
    leaves[((size_t)ch * Bb + b) * 2 + 1] = half + l1 - m - L;
  }
}

// ----------------- big bf16 MFMA GEMM: logits = hidd @ W_out ----------------
// m97 structure: 128x128 tile, BK=64, global_load_lds width 16, XOR-swizzled
// LDS chunk placement (conflict-free b128 frag reads), 16x16x32 bf16 MFMA.
__global__ __launch_bounds__(256) void k_gemm(
    const unsigned short* __restrict__ A, const unsigned short* __restrict__ Bt,
    const float* __restrict__ bout, float* __restrict__ out, int Mvalid) {
  __shared__ short As[128 * 64];
  __shared__ short Bs[128 * 64];
  int tid = threadIdx.x;
  int lane = tid & 63, w = tid >> 6;
  int wm = w & 1, wn = w >> 1;
  int R0 = blockIdx.x * 128, C0 = blockIdx.y * 128;
  f32x4 acc[4][4];
#pragma unroll
  for (int i = 0; i < 4; i++)
#pragma unroll
    for (int j = 0; j < 4; j++) acc[i][j] = 0.f;
  int quad = lane >> 4, l15 = lane & 15;
  int srow = lane >> 3;  // 0..7 within 8-row staging group
  int kc = lane & 7;     // 16B-chunk slot within row
  for (int kb = 0; kb < 16; kb++) {
    int k0 = kb * 64;
#pragma unroll
    for (int i = 0; i < 4; i++) {
      int rowb = w * 32 + i * 8;
      int m = rowb + srow;
      int kcx = kc ^ (m & 7);  // slot s holds global chunk s^(m&7)
      const unsigned short* ga = A + (size_t)(R0 + m) * Hd + k0 + kcx * 8;
      const unsigned short* gb = Bt + (size_t)(C0 + m) * Hd + k0 + kcx * 8;
      __builtin_amdgcn_global_load_lds(
          (__attribute__((address_space(1))) void*)ga,
          (__attribute__((address_space(3))) void*)&As[rowb * 64], 16, 0, 0);
      __builtin_amdgcn_global_load_lds(
          (__attribute__((address_space(1))) void*)gb,
          (__attribute__((address_space(3))) void*)&Bs[rowb * 64], 16, 0, 0);
    }
    __syncthreads();
#pragma unroll
    for (int ksi = 0; ksi < 2; ksi++) {
      bf16x8 af[4], bfr[4];
      int kidx = ksi * 4 + quad;
#pragma unroll
      for (int i = 0; i < 4; i++) {
        int m = wm * 64 + i * 16 + l15;
        af[i] = *(const bf16x8*)&As[m * 64 + (kidx ^ (m & 7)) * 8];
      }
#pragma unroll
      for (int j = 0; j < 4; j++) {
        int n = wn * 64 + j * 16 + l15;
        bfr[j] = *(const bf16x8*)&Bs[n * 64 + (kidx ^ (n & 7)) * 8];
      }
#pragma unroll
      for (int i = 0; i < 4; i++)
#pragma unroll
        for (int j = 0; j < 4; j++)
          acc[i][j] = __builtin_amdgcn_mfma_f32_16x16x32_bf16(af[i], bfr[j],
                                                              acc[i][j], 0, 0, 0);
    }
    __syncthreads();
  }
  // C/D layout: col = lane&15, row = quad*4 + reg  [m89-verified]
#pragma unroll
  for (int j = 0; j < 4; j++) {
    int col = C0 + wn * 64 + j * 16 + l15;
    float bo = bout[col];
#pragma unroll
    for (int i = 0; i < 4; i++) {
      int rowb = R0 + wm * 64 + i * 16 + quad * 4;
#pragma unroll
      for (int r = 0; r < 4; r++) {
        int row = rowb + r;
        if (row < Mvalid) out[(size_t)row * Vv + col] = acc[i][j][r] + bo;
      }
    }
  }
}

// --------------------- per-row max + logsumexp ------------------------------
__global__ void k_rowstats(const float* __restrict__ out, float* __restrict__ st) {
  __shared__ float ms[256], ss[256];
  int r = blockIdx.x, tid = threadIdx.x;
  const float* row = out + (size_t)r * Vv;
  float m = -1e30f, s = 0.f;
  for (int i = tid; i < Vv; i += 256) {
    float x = row[i];
    if (x > m) { s = s * expf(m - x) + 1.f; m = x; }
    else s += expf(x - m);
  }
  ms[tid] = m; ss[tid] = s;
  __syncthreads();
  for (int o = 128; o; o >>= 1) {
    if (tid < o) {
      float m2 = ms[tid + o], s2 = ss[tid + o];
      float M = fmaxf(ms[tid], m2);
      ss[tid] = ss[tid] * expf(ms[tid] - M) + s2 * expf(m2 - M);
      ms[tid] = M;
    }
    __syncthreads();
  }
  if (tid == 0) st[r] = ms[0] + logf(ss[0]);
}

// --------------------------- normalize in place -----------------------------
__global__ void k_norm(float* __restrict__ out, const float* __restrict__ st) {
  int r = blockIdx.y;
  int i = blockIdx.x * 256 + threadIdx.x;
  if (i < Vv / 4) {
    float sub = st[r];
    f4* p = (f4*)(out + (size_t)r * Vv) + i;
    f4 v = *p;
    v -= sub;
    *p = v;
  }
}

// ------------------------- static index outputs -----------------------------
__global__ void k_idx(float* __restrict__ dst) {
  int total = DS.nStart + DS.nEnd + 2 * DS.nS;
  for (int i = threadIdx.x; i < total; i += 256) {
    int v;
    if (i < DS.nStart) v = DS.startIdx[i];
    else if (i < DS.nStart + DS.nEnd) v = DS.endIdx[i - DS.nStart];
    else if (i < DS.nStart + DS.nEnd + DS.nS) v = DS.sOut[i - DS.nStart - DS.nEnd];
    else v = DS.sIn[i - DS.nStart - DS.nEnd - DS.nS];
    dst[i] = (float)v;
  }
}

// ---------------------------------------------------------------------------
extern "C" void kernel_launch(void* const* d_in, const int* in_sizes, int n_in,
                              void* d_out, int out_size, void* d_ws, size_t ws_size,
                              hipStream_t stream) {
  (void)in_sizes; (void)n_in; (void)out_size; (void)ws_size;
  const float* x    = (const float*)d_in[0];
  const float* Win  = (const float*)d_in[1];
  const float* bin  = (const float*)d_in[2];
  const float* Wg   = (const float*)d_in[3];
  const float* bg   = (const float*)d_in[4];
  const float* Wc   = (const float*)d_in[5];
  const float* bc   = (const float*)d_in[6];
  const float* lng  = (const float*)d_in[7];
  const float* lnb  = (const float*)d_in[8];
  const float* Wl   = (const float*)d_in[9];
  const float* bl   = (const float*)d_in[10];
  const float* Wout = (const float*)d_in[11];
  const float* bout = (const float*)d_in[12];
  float* out = (float*)d_out;

  constexpr int T = HS.T;                        // 351
  constexpr int Mrows = T * Bb;                  // 2808
  constexpr int Mt = ((Mrows + 127) / 128) * 128;  // 2816

  char* ws = (char*)d_ws;
  unsigned short* Wt = (unsigned short*)ws;  ws += (size_t)Vv * Hd * 2;
  float* hidd = (float*)ws;                  ws += (size_t)Mt * Hd * 4;
  unsigned short* hiddb = (unsigned short*)ws; ws += (size_t)Mt * Hd * 2;
  float* gbuf = (float*)ws;                  ws += (size_t)Bb * Hd * 4;
  float* gW = (float*)ws;                    ws += (size_t)Bb * 2048 * 4;
  float* zp = (float*)ws;                    ws += (size_t)512 * Bb * 1024 * 4;
  float* st = (float*)ws;                    ws += (size_t)Mt * 4;

  float* leaves = out + (size_t)Mrows * Vv;
  float* idxdst = leaves + (size_t)Mrows * 2;

  k_wout_t<<<dim3(Vv / 32, Hd / 32), dim3(32, 8), 0, stream>>>(Wout, Wt);
  k_init<<<dim3(8, 2), dim3(256), 0, stream>>>(x, Wg, bg, Win, bin, gbuf, hidd, hiddb);
  k_gw<<<dim3(16), dim3(256), 0, stream>>>(gbuf, Wc, bc, gW);
  k_leaf0<<<dim3(1), dim3(512), 0, stream>>>(hidd, Wl, bl, leaves);

  for (int l = 1; l < DEPTH; l++) {
    int Pc = HS.parCnt[l - 1];
    int KS = 64;
    while (2 * Pc * KS > 512) KS >>= 1;
    int kshift = 0;
    { int kc2 = 1024 / KS; while ((1 << kshift) < kc2) kshift++; }
    PR pr{};
    for (int i = 0; i < Pc; i++) pr.v[i] = HS.parRows[l - 1][i];
    k_cell<<<dim3(2, Pc, KS), dim3(256), 0, stream>>>(hidd, Wc, zp, pr, KS, kshift);
    k_ln<<<dim3(2 * Pc, Bb), dim3(256), 0, stream>>>(zp, gW, lng, lnb, Wl, bl,
                                                     hidd, hiddb, leaves, pr, KS,
                                                     HS.lvlOff[l]);
  }

  k_gemm<<<dim3(Mt / 128, Vv / 128), dim3(256), 0, stream>>>(hiddb, Wt, bout, out, Mrows);
  k_rowstats<<<dim3(Mrows), dim3(256), 0, stream>>>(out, st);
  k_norm<<<dim3(32, Mrows), dim3(256), 0, stream>>>(out, st);
  k_idx<<<dim3(1), dim3(256), 0, stream>>>(idxdst);
}

// Round 2
// 1407.051 us; speedup vs baseline: 1.1661x; 1.1661x over previous
//
#include <hip/hip_runtime.h>
#include <cstdint>
#include <cstddef>

// ---------------------------------------------------------------------------
// OrderedMemoryDecoder (DEPTH=14, B=8, H=1024, V=32000) for gfx950.
// R2: tree levels as bf16 MFMA GEMM vs pre-transposed Wct (W_cell read once
// per level); log-softmax row stats fused into big-GEMM epilogue.
// ---------------------------------------------------------------------------

typedef __attribute__((ext_vector_type(4))) float   f4;
typedef __attribute__((ext_vector_type(4))) float   f32x4;
typedef __attribute__((ext_vector_type(8))) __bf16  bf16x8;
typedef __attribute__((ext_vector_type(4))) unsigned short us4;

constexpr int DEPTH = 14;
constexpr int Bb = 8;
constexpr int Hd = 1024;
constexpr int Vv = 32000;
constexpr int NT = Vv / 128;   // 250 N-tiles in big GEMM
constexpr int MAXT = 512;
constexpr int MAXS = 4096;
constexpr int MAXP = 32;

struct SB {
  int lvlOff[DEPTH + 1];
  int lvlK[DEPTH];
  int len[MAXT];
  int lch[MAXT], rch[MAXT];
  int parCnt[DEPTH];
  int parRows[DEPTH][MAXP];
  int T;
  int nS;
  int sOut[MAXS], sIn[MAXS];
  int nStart, nEnd;
  int startIdx[16], endIdx[16];
};

constexpr int ceil75(int L) {
  constexpr int t[14] = {0, 1, 2, 3, 3, 4, 4, 5, 5, 6, 6, 7, 7, 7};
  return t[L];
}

constexpr SB build() {
  SB s{};
  for (int i = 0; i < MAXT; i++) { s.lch[i] = -1; s.rch[i] = -1; }
  s.lvlOff[0] = 0; s.lvlK[0] = 1; s.len[0] = DEPTH;
  for (int l = 0; l < DEPTH - 1; l++) {
    int off = s.lvlOff[l], K = s.lvlK[l];
    int nxt = off + K, cnt = 0;
    for (int i = 0; i < K; i++) {
      int g = off + i;
      if (s.len[g] > 1) {
        int gl = nxt + 2 * cnt, gr = gl + 1;
        s.lch[g] = gl; s.rch[g] = gr;
        s.len[gl] = ceil75(s.len[g] - 1);
        s.len[gr] = s.len[g] - 1;
        s.parRows[l][cnt] = g;
        cnt++;
      }
    }
    s.parCnt[l] = cnt;
    s.lvlOff[l + 1] = nxt;
    s.lvlK[l + 1] = 2 * cnt;
  }
  s.T = s.lvlOff[DEPTH - 1] + s.lvlK[DEPTH - 1];
  s.nS = 0;
  for (int l = DEPTH - 2; l >= 0; l--) {
    for (int pi = 0; pi < s.parCnt[l]; pi++) {
      int g = s.parRows[l][pi];
      for (int u = s.lch[g]; u != -1; u = s.rch[u])
        for (int v = s.rch[g]; v != -1; v = s.lch[v]) {
          s.sOut[s.nS] = u; s.sIn[s.nS] = v; s.nS++;
        }
    }
  }
  s.nStart = 0;
  for (int u = 0; u != -1; u = s.lch[u]) s.startIdx[s.nStart++] = u;
  s.nEnd = 0;
  for (int u = 0; u != -1; u = s.rch[u]) s.endIdx[s.nEnd++] = u;
  return s;
}

constexpr SB HS = build();
__device__ const SB DS = build();

struct PR { int v[MAXP]; };

__device__ __forceinline__ unsigned short f2bf(float f) {
  union { float f; unsigned u; } v; v.f = f;
  unsigned r = v.u + 0x7fffu + ((v.u >> 16) & 1u);  // RNE
  return (unsigned short)(r >> 16);
}

// --------------------------- W_out -> bf16, transposed ----------------------
__global__ void k_wout_t(const float* __restrict__ Wout,
                         unsigned short* __restrict__ Wt) {
  __shared__ float t[32][33];
  int tx = threadIdx.x, ty = threadIdx.y;
  int n0 = blockIdx.x * 32, k0 = blockIdx.y * 32;
  for (int i = 0; i < 4; i++)
    t[ty + 8 * i][tx] = Wout[(size_t)(k0 + ty + 8 * i) * Vv + n0 + tx];
  __syncthreads();
  for (int i = 0; i < 4; i++)
    Wt[(size_t)(n0 + ty + 8 * i) * Hd + k0 + tx] = f2bf(t[tx][ty + 8 * i]);
}

// --------------- W_cell[:1024,:] -> bf16, transposed [2048][1024] -----------
__global__ void k_wct(const float* __restrict__ Wc,
                      unsigned short* __restrict__ Wct) {
  __shared__ float t[32][33];
  int tx = threadIdx.x, ty = threadIdx.y;
  int n0 = blockIdx.x * 32, k0 = blockIdx.y * 32;
  for (int i = 0; i < 4; i++)
    t[ty + 8 * i][tx] = Wc[(size_t)(k0 + ty + 8 * i) * 2048 + n0 + tx];
  __syncthreads();
  for (int i = 0; i < 4; i++)
    Wct[(size_t)(n0 + ty + 8 * i) * Hd + k0 + tx] = f2bf(t[tx][ty + 8 * i]);
}

// ------------------------------ g and h0 ------------------------------------
__global__ void k_init(const float* __restrict__ x, const float* __restrict__ Wg,
                       const float* __restrict__ bg, const float* __restrict__ Win,
                       const float* __restrict__ bin, float* __restrict__ gbuf,
                       float* __restrict__ hidd, unsigned short* __restrict__ hiddb) {
  __shared__ float xs[Bb * Hd];
  __shared__ float part[Bb][128];
  int tid = threadIdx.x;
  int mat = blockIdx.y;
  const float* W = mat ? Win : Wg;
  const float* bias = mat ? bin : bg;
  for (int i = tid; i < Bb * Hd; i += 256) xs[i] = x[i];
  __syncthreads();
  int c = tid & 127, kh = tid >> 7;
  int col = blockIdx.x * 128 + c;
  float acc[Bb];
#pragma unroll
  for (int b = 0; b < Bb; b++) acc[b] = 0.f;
  for (int k = kh * 512; k < kh * 512 + 512; k++) {
    float w = W[(size_t)k * Hd + col];
#pragma unroll
    for (int b = 0; b < Bb; b++) acc[b] += xs[b * Hd + k] * w;
  }
  if (kh == 1)
    for (int b = 0; b < Bb; b++) part[b][c] = acc[b];
  __syncthreads();
  if (kh == 0) {
    for (int b = 0; b < Bb; b++) {
      float v = acc[b] + part[b][c] + bias[col];
      if (mat == 0) gbuf[b * Hd + col] = v;
      else { hidd[(size_t)b * Hd + col] = v; hiddb[(size_t)b * Hd + col] = f2bf(v); }
    }
  }
}

// --------------------- gW = g @ W_cell[1024:,:] + b_cell --------------------
__global__ void k_gw(const float* __restrict__ gbuf, const float* __restrict__ Wc,
                     const float* __restrict__ bc, float* __restrict__ gW) {
  __shared__ float xs[Bb * Hd];
  __shared__ float part[Bb][128];
  int tid = threadIdx.x;
  for (int i = tid; i < Bb * Hd; i += 256) xs[i] = gbuf[i];
  __syncthreads();
  int c = tid & 127, kh = tid >> 7;
  int col = blockIdx.x * 128 + c;
  float acc[Bb];
#pragma unroll
  for (int b = 0; b < Bb; b++) acc[b] = 0.f;
  for (int k = kh * 512; k < kh * 512 + 512; k++) {
    float w = Wc[(size_t)(Hd + k) * 2048 + col];
#pragma unroll
    for (int b = 0; b < Bb; b++) acc[b] += xs[b * Hd + k] * w;
  }
  if (kh == 1)
    for (int b = 0; b < Bb; b++) part[b][c] = acc[b];
  __syncthreads();
  if (kh == 0)
    for (int b = 0; b < Bb; b++)
      gW[(size_t)b * 2048 + col] = acc[b] + part[b][c] + bc[col];
}

// ---------------------- level-0 leaf log-softmax ----------------------------
__global__ void k_leaf0(const float* __restrict__ hidd, const float* __restrict__ Wl,
                        const float* __restrict__ bl, float* __restrict__ leaves) {
  int b = threadIdx.x >> 6, lane = threadIdx.x & 63;
  float d0 = 0.f, d1 = 0.f;
  for (int k = lane; k < Hd; k += 64) {
    float h = hidd[(size_t)b * Hd + k];
    d0 += h * Wl[2 * k];
    d1 += h * Wl[2 * k + 1];
  }
  for (int off = 32; off; off >>= 1) {
    d0 += __shfl_down(d0, off);
    d1 += __shfl_down(d1, off);
  }
  if (lane == 0) {
    float l0 = d0 + bl[0], l1 = d1 + bl[1];
    float m = fmaxf(l0, l1);
    float L = logf(expf(l0 - m) + expf(l1 - m));
    leaves[b * 2 + 0] = l0 - m - L;
    leaves[b * 2 + 1] = l1 - m - L;
  }
}

// -------- tree cell GEMM: z[m][0:2048] = h[parent rows] @ Wc[:1024,:] -------
// bf16 MFMA, m97 structure; A rows gathered via pr. zbuf fp32 [Mtot][2048].
__global__ __launch_bounds__(256) void k_cellg(
    const unsigned short* __restrict__ A, const unsigned short* __restrict__ Bt,
    float* __restrict__ zbuf, PR pr, int Mtot) {
  __shared__ short As[128 * 64];
  __shared__ short Bs[128 * 64];
  int tid = threadIdx.x;
  int lane = tid & 63, w = tid >> 6;
  int wm = w & 1, wn = w >> 1;
  int R0 = blockIdx.x * 128, C0 = blockIdx.y * 128;
  f32x4 acc[4][4];
#pragma unroll
  for (int i = 0; i < 4; i++)
#pragma unroll
    for (int j = 0; j < 4; j++) acc[i][j] = 0.f;
  int quad = lane >> 4, l15 = lane & 15;
  int srow = lane >> 3;
  int kc = lane & 7;
  for (int kb = 0; kb < 16; kb++) {
    int k0 = kb * 64;
#pragma unroll
    for (int i = 0; i < 4; i++) {
      int rowb = w * 32 + i * 8;
      int m = rowb + srow;
      int kcx = kc ^ (m & 7);
      int gr = R0 + m;
      int grc = gr < Mtot ? gr : 0;
      int arow = pr.v[grc >> 3] * Bb + (grc & 7);
      const unsigned short* ga = A + (size_t)arow * Hd + k0 + kcx * 8;
      const unsigned short* gb = Bt + (size_t)(C0 + m) * Hd + k0 + kcx * 8;
      __builtin_amdgcn_global_load_lds(
          (__attribute__((address_space(1))) void*)ga,
          (__attribute__((address_space(3))) void*)&As[rowb * 64], 16, 0, 0);
      __builtin_amdgcn_global_load_lds(
          (__attribute__((address_space(1))) void*)gb,
          (__attribute__((address_space(3))) void*)&Bs[rowb * 64], 16, 0, 0);
    }
    __syncthreads();
#pragma unroll
    for (int ksi = 0; ksi < 2; ksi++) {
      bf16x8 af[4], bfr[4];
      int kidx = ksi * 4 + quad;
#pragma unroll
      for (int i = 0; i < 4; i++) {
        int m = wm * 64 + i * 16 + l15;
        af[i] = *(const bf16x8*)&As[m * 64 + (kidx ^ (m & 7)) * 8];
      }
#pragma unroll
      for (int j = 0; j < 4; j++) {
        int n = wn * 64 + j * 16 + l15;
        bfr[j] = *(const bf16x8*)&Bs[n * 64 + (kidx ^ (n & 7)) * 8];
      }
#pragma unroll
      for (int i = 0; i < 4; i++)
#pragma unroll
        for (int j = 0; j < 4; j++)
          acc[i][j] = __builtin_amdgcn_mfma_f32_16x16x32_bf16(af[i], bfr[j],
                                                              acc[i][j], 0, 0, 0);
    }
    __syncthreads();
  }
#pragma unroll
  for (int j = 0; j < 4; j++) {
    int col = C0 + wn * 64 + j * 16 + l15;
#pragma unroll
    for (int i = 0; i < 4; i++) {
      int rowb = R0 + wm * 64 + i * 16 + quad * 4;
#pragma unroll
      for (int r = 0; r < 4; r++) {
        int row = rowb + r;
        if (row < Mtot) zbuf[(size_t)row * 2048 + col] = acc[i][j][r];
      }
    }
  }
}

// ---------- tree LN+tanh+leaf: one block per (child node, batch) ------------
__global__ void k_ln2(const float* __restrict__ zbuf, const float* __restrict__ gW,
                      const float* __restrict__ lng, const float* __restrict__ lnb,
                      const float* __restrict__ Wl, const float* __restrict__ bl,
                      float* __restrict__ hidd, unsigned short* __restrict__ hiddb,
                      float* __restrict__ leaves, PR pr, int lvlOff) {
  __shared__ float r1[256], r2[256];
  int tid = threadIdx.x;
  int node = blockIdx.x, b = blockIdx.y;
  int cg = node & 1, p = node >> 1;
  int gp = pr.v[p];
  int ch = lvlOff + node;
  int m = p * Bb + b;
  int j0 = tid * 4;
  f4 z = *(const f4*)&zbuf[(size_t)m * 2048 + cg * 1024 + j0];
  z += *(const f4*)&gW[(size_t)b * 2048 + cg * 1024 + j0];
  float s = z.x + z.y + z.z + z.w;
  float s2 = z.x * z.x + z.y * z.y + z.z * z.z + z.w * z.w;
  r1[tid] = s; r2[tid] = s2;
  __syncthreads();
  for (int o = 128; o; o >>= 1) {
    if (tid < o) { r1[tid] += r1[tid + o]; r2[tid] += r2[tid + o]; }
    __syncthreads();
  }
  float mu = r1[0] * (1.f / 1024.f);
  float var = r2[0] * (1.f / 1024.f) - mu * mu;
  float rs = rsqrtf(var + 1e-5f);
  __syncthreads();
  f4 lgv = *(const f4*)&lng[j0];
  f4 lbv = *(const f4*)&lnb[j0];
  f4 y;
  y.x = tanhf((z.x - mu) * rs * lgv.x + lbv.x);
  y.y = tanhf((z.y - mu) * rs * lgv.y + lbv.y);
  y.z = tanhf((z.z - mu) * rs * lgv.z + lbv.z);
  y.w = tanhf((z.w - mu) * rs * lgv.w + lbv.w);
  *(f4*)&hidd[((size_t)ch * Bb + b) * Hd + j0] = y;
  us4 yb;
  yb.x = f2bf(y.x); yb.y = f2bf(y.y); yb.z = f2bf(y.z); yb.w = f2bf(y.w);
  *(us4*)&hiddb[((size_t)ch * Bb + b) * Hd + j0] = yb;
  f4 wA = *(const f4*)&Wl[j0 * 2];
  f4 wB = *(const f4*)&Wl[j0 * 2 + 4];
  float d0 = y.x * wA.x + y.y * wA.z + y.z * wB.x + y.w * wB.z;
  float d1 = y.x * wA.y + y.y * wA.w + y.z * wB.y + y.w * wB.w;
  r1[tid] = d0; r2[tid] = d1;
  __syncthreads();
  for (int o = 128; o; o >>= 1) {
    if (tid < o) { r1[tid] += r1[tid + o]; r2[tid] += r2[tid + o]; }
    __syncthreads();
  }
  if (tid == 0) {
    float l0 = r1[0] + bl[0], l1 = r2[0] + bl[1];
    float mm = fmaxf(l0, l1);
    float L = logf(expf(l0 - mm) + expf(l1 - mm));
    float half = 0.5f * leaves[((size_t)gp * Bb + b) * 2 + 1];
    leaves[((size_t)ch * Bb + b) * 2 + 0] = half + l0 - mm - L;
    leaves[((size_t)ch * Bb + b) * 2 + 1] = half + l1 - mm - L;
  }
}

// ----------------- big bf16 MFMA GEMM + fused softmax partials --------------
__global__ __launch_bounds__(256) void k_gemm(
    const unsigned short* __restrict__ A, const unsigned short* __restrict__ Bt,
    const float* __restrict__ bout, float* __restrict__ out,
    float2* __restrict__ ptile, int Mvalid) {
  __shared__ short As[128 * 64];
  __shared__ short Bs[128 * 64];
  int tid = threadIdx.x;
  int lane = tid & 63, w = tid >> 6;
  int wm = w & 1, wn = w >> 1;
  int R0 = blockIdx.x * 128, C0 = blockIdx.y * 128;
  f32x4 acc[4][4];
#pragma unroll
  for (int i = 0; i < 4; i++)
#pragma unroll
    for (int j = 0; j < 4; j++) acc[i][j] = 0.f;
  int quad = lane >> 4, l15 = lane & 15;
  int srow = lane >> 3;
  int kc = lane & 7;
  for (int kb = 0; kb < 16; kb++) {
    int k0 = kb * 64;
#pragma unroll
    for (int i = 0; i < 4; i++) {
      int rowb = w * 32 + i * 8;
      int m = rowb + srow;
      int kcx = kc ^ (m & 7);
      const unsigned short* ga = A + (size_t)(R0 + m) * Hd + k0 + kcx * 8;
      const unsigned short* gb = Bt + (size_t)(C0 + m) * Hd + k0 + kcx * 8;
      __builtin_amdgcn_global_load_lds(
          (__attribute__((address_space(1))) void*)ga,
          (__attribute__((address_space(3))) void*)&As[rowb * 64], 16, 0, 0);
      __builtin_amdgcn_global_load_lds(
          (__attribute__((address_space(1))) void*)gb,
          (__attribute__((address_space(3))) void*)&Bs[rowb * 64], 16, 0, 0);
    }
    __syncthreads();
#pragma unroll
    for (int ksi = 0; ksi < 2; ksi++) {
      bf16x8 af[4], bfr[4];
      int kidx = ksi * 4 + quad;
#pragma unroll
      for (int i = 0; i < 4; i++) {
        int m = wm * 64 + i * 16 + l15;
        af[i] = *(const bf16x8*)&As[m * 64 + (kidx ^ (m & 7)) * 8];
      }
#pragma unroll
      for (int j = 0; j < 4; j++) {
        int n = wn * 64 + j * 16 + l15;
        bfr[j] = *(const bf16x8*)&Bs[n * 64 + (kidx ^ (n & 7)) * 8];
      }
#pragma unroll
      for (int i = 0; i < 4; i++)
#pragma unroll
        for (int j = 0; j < 4; j++)
          acc[i][j] = __builtin_amdgcn_mfma_f32_16x16x32_bf16(af[i], bfr[j],
                                                              acc[i][j], 0, 0, 0);
    }
    __syncthreads();
  }
  // Epilogue: bias, store, per-row partial (max, sumexp) over this block's
  // 128 cols. C/D layout: col = lane&15, row = quad*4 + reg [m89].
  float2* sred = (float2*)As;  // [2 wn][128 local rows]; safe: trailing sync above
  float bo[4];
#pragma unroll
  for (int j = 0; j < 4; j++) bo[j] = bout[C0 + wn * 64 + j * 16 + l15];
#pragma unroll
  for (int i = 0; i < 4; i++) {
#pragma unroll
    for (int r = 0; r < 4; r++) {
      int lr = wm * 64 + i * 16 + quad * 4 + r;
      int row = R0 + lr;
      float v0 = acc[i][0][r] + bo[0];
      float v1 = acc[i][1][r] + bo[1];
      float v2 = acc[i][2][r] + bo[2];
      float v3 = acc[i][3][r] + bo[3];
      float mx = fmaxf(fmaxf(v0, v1), fmaxf(v2, v3));
      float sm = expf(v0 - mx) + expf(v1 - mx) + expf(v2 - mx) + expf(v3 - mx);
      if (row < Mvalid) {
        size_t base = (size_t)row * Vv + C0 + wn * 64 + l15;
        out[base + 0]  = v0;
        out[base + 16] = v1;
        out[base + 32] = v2;
        out[base + 48] = v3;
      }
      // merge across the 16-lane l15 group (same rows, disjoint cols)
#pragma unroll
      for (int d = 1; d < 16; d <<= 1) {
        float omx = __shfl_xor(mx, d);
        float osm = __shfl_xor(sm, d);
        float M = fmaxf(mx, omx);
        sm = sm * expf(mx - M) + osm * expf(omx - M);
        mx = M;
      }
      if (l15 == 0) { sred[wn * 128 + lr].x = mx; sred[wn * 128 + lr].y = sm; }
    }
  }
  __syncthreads();
  if (tid < 128) {
    float2 a = sred[tid], c = sred[128 + tid];
    float M = fmaxf(a.x, c.x);
    float S = a.y * expf(a.x - M) + c.y * expf(c.x - M);
    float2 o; o.x = M; o.y = S;
    ptile[(size_t)(R0 + tid) * NT + blockIdx.y] = o;
  }
}

// --------------------- reduce partial stats -> row LSE ----------------------
__global__ void k_lse(const float2* __restrict__ ptile, float* __restrict__ st) {
  __shared__ float ms[256], ss[256];
  int r = blockIdx.x, tid = threadIdx.x;
  float mx = -3e38f, sm = 0.f;
  for (int t = tid; t < NT; t += 256) {
    float2 e = ptile[(size_t)r * NT + t];
    float M = fmaxf(mx, e.x);
    sm = sm * expf(mx - M) + e.y * expf(e.x - M);
    mx = M;
  }
  ms[tid] = mx; ss[tid] = sm;
  __syncthreads();
  for (int o = 128; o; o >>= 1) {
    if (tid < o) {
      float m2 = ms[tid + o], s2 = ss[tid + o];
      float M = fmaxf(ms[tid], m2);
      ss[tid] = ss[tid] * expf(ms[tid] - M) + s2 * expf(m2 - M);
      ms[tid] = M;
    }
    __syncthreads();
  }
  if (tid == 0) st[r] = ms[0] + logf(ss[0]);
}

// --------------------------- normalize in place -----------------------------
__global__ void k_norm(float* __restrict__ out, const float* __restrict__ st) {
  int r = blockIdx.y;
  int i = blockIdx.x * 256 + threadIdx.x;
  if (i < Vv / 4) {
    float sub = st[r];
    f4* p = (f4*)(out + (size_t)r * Vv) + i;
    f4 v = *p;
    v -= sub;
    *p = v;
  }
}

// ------------------------- static index outputs -----------------------------
__global__ void k_idx(float* __restrict__ dst) {
  int total = DS.nStart + DS.nEnd + 2 * DS.nS;
  for (int i = threadIdx.x; i < total; i += 256) {
    int v;
    if (i < DS.nStart) v = DS.startIdx[i];
    else if (i < DS.nStart + DS.nEnd) v = DS.endIdx[i - DS.nStart];
    else if (i < DS.nStart + DS.nEnd + DS.nS) v = DS.sOut[i - DS.nStart - DS.nEnd];
    else v = DS.sIn[i - DS.nStart - DS.nEnd - DS.nS];
    dst[i] = (float)v;
  }
}

// ---------------------------------------------------------------------------
extern "C" void kernel_launch(void* const* d_in, const int* in_sizes, int n_in,
                              void* d_out, int out_size, void* d_ws, size_t ws_size,
                              hipStream_t stream) {
  (void)in_sizes; (void)n_in; (void)out_size; (void)ws_size;
  const float* x    = (const float*)d_in[0];
  const float* Win  = (const float*)d_in[1];
  const float* bin  = (const float*)d_in[2];
  const float* Wg   = (const float*)d_in[3];
  const float* bg   = (const float*)d_in[4];
  const float* Wc   = (const float*)d_in[5];
  const float* bc   = (const float*)d_in[6];
  const float* lng  = (const float*)d_in[7];
  const float* lnb  = (const float*)d_in[8];
  const float* Wl   = (const float*)d_in[9];
  const float* bl   = (const float*)d_in[10];
  const float* Wout = (const float*)d_in[11];
  const float* bout = (const float*)d_in[12];
  float* out = (float*)d_out;

  constexpr int T = HS.T;                          // 351
  constexpr int Mrows = T * Bb;                    // 2808
  constexpr int Mt = ((Mrows + 127) / 128) * 128;  // 2816

  char* ws = (char*)d_ws;
  unsigned short* Wt = (unsigned short*)ws;    ws += (size_t)Vv * Hd * 2;
  unsigned short* Wct = (unsigned short*)ws;   ws += (size_t)2048 * Hd * 2;
  float* hidd = (float*)ws;                    ws += (size_t)Mt * Hd * 4;
  unsigned short* hiddb = (unsigned short*)ws; ws += (size_t)Mt * Hd * 2;
  float* gbuf = (float*)ws;                    ws += (size_t)Bb * Hd * 4;
  float* gW = (float*)ws;                      ws += (size_t)Bb * 2048 * 4;
  float* zbuf = (float*)ws;                    ws += (size_t)256 * 2048 * 4;
  float2* ptile = (float2*)ws;                 ws += (size_t)Mt * NT * 8;
  float* st = (float*)ws;                      ws += (size_t)Mt * 4;

  float* leaves = out + (size_t)Mrows * Vv;
  float* idxdst = leaves + (size_t)Mrows * 2;

  k_wout_t<<<dim3(Vv / 32, Hd / 32), dim3(32, 8), 0, stream>>>(Wout, Wt);
  k_wct<<<dim3(2048 / 32, Hd / 32), dim3(32, 8), 0, stream>>>(Wc, Wct);
  k_init<<<dim3(8, 2), dim3(256), 0, stream>>>(x, Wg, bg, Win, bin, gbuf, hidd, hiddb);
  k_gw<<<dim3(16), dim3(256), 0, stream>>>(gbuf, Wc, bc, gW);
  k_leaf0<<<dim3(1), dim3(512), 0, stream>>>(hidd, Wl, bl, leaves);

  for (int l = 1; l < DEPTH; l++) {
    int Pc = HS.parCnt[l - 1];
    int Mtot = Pc * Bb;
    int Mtiles = (Mtot + 127) / 128;
    PR pr{};
    for (int i = 0; i < Pc; i++) pr.v[i] = HS.parRows[l - 1][i];
    k_cellg<<<dim3(Mtiles, 16), dim3(256), 0, stream>>>(hiddb, Wct, zbuf, pr, Mtot);
    k_ln2<<<dim3(2 * Pc, Bb), dim3(256), 0, stream>>>(zbuf, gW, lng, lnb, Wl, bl,
                                                      hidd, hiddb, leaves, pr,
                                                      HS.lvlOff[l]);
  }

  k_gemm<<<dim3(Mt / 128, Vv / 128), dim3(256), 0, stream>>>(hiddb, Wt, bout, out,
                                                             ptile, Mrows);
  k_lse<<<dim3(Mrows), dim3(256), 0, stream>>>(ptile, st);
  k_norm<<<dim3(32, Mrows), dim3(256), 0, stream>>>(out, st);
  k_idx<<<dim3(1), dim3(256), 0, stream>>>(idxdst);
}